// Round 1
// baseline (1594.403 us; speedup 1.0000x reference)
//
#include <hip/hip_runtime.h>

#define TSEQ 4096
#define DE   1024
#define NH   16
#define DH   64

typedef float4 f4;

// C[M,N] = A[M,K] @ B[K,N] + bias[N]; 64x64 tile, 256 threads, 4x4 micro-tile, K-tile 16
__global__ __launch_bounds__(256) void gemm_bias_kernel(
    const float* __restrict__ A, const float* __restrict__ B,
    const float* __restrict__ bias, float* __restrict__ C,
    int M, int N, int K)
{
    __shared__ float As[64][20];   // stride 20 floats: rows 16B-aligned, ty-groups 2-way (free)
    __shared__ float Bs[16][64];
    const int tid = threadIdx.x;
    const int tx = tid & 15, ty = tid >> 4;
    const int m0 = blockIdx.y * 64;
    const int n0 = blockIdx.x * 64;

    float acc[4][4] = {{0.f}};

    for (int k0 = 0; k0 < K; k0 += 16) {
        {
            const int arow = tid >> 2, ac = (tid & 3) * 4;
            f4 av = *reinterpret_cast<const f4*>(&A[(size_t)(m0 + arow) * K + k0 + ac]);
            *reinterpret_cast<f4*>(&As[arow][ac]) = av;
            const int brow = tid >> 4, bc = (tid & 15) * 4;
            f4 bv = *reinterpret_cast<const f4*>(&B[(size_t)(k0 + brow) * N + n0 + bc]);
            *reinterpret_cast<f4*>(&Bs[brow][bc]) = bv;
        }
        __syncthreads();
        #pragma unroll
        for (int kk4 = 0; kk4 < 4; ++kk4) {
            f4 a[4], b[4];
            #pragma unroll
            for (int i = 0; i < 4; ++i)
                a[i] = *reinterpret_cast<const f4*>(&As[ty * 4 + i][kk4 * 4]);
            #pragma unroll
            for (int k = 0; k < 4; ++k)
                b[k] = *reinterpret_cast<const f4*>(&Bs[kk4 * 4 + k][tx * 4]);
            #pragma unroll
            for (int i = 0; i < 4; ++i) {
                const float av[4] = {a[i].x, a[i].y, a[i].z, a[i].w};
                #pragma unroll
                for (int k = 0; k < 4; ++k) {
                    acc[i][0] += av[k] * b[k].x;
                    acc[i][1] += av[k] * b[k].y;
                    acc[i][2] += av[k] * b[k].z;
                    acc[i][3] += av[k] * b[k].w;
                }
            }
        }
        __syncthreads();
    }
    #pragma unroll
    for (int i = 0; i < 4; ++i) {
        const int m = m0 + ty * 4 + i, n = n0 + tx * 4;
        f4 bv = *reinterpret_cast<const f4*>(&bias[n]);
        f4 o = make_float4(acc[i][0] + bv.x, acc[i][1] + bv.y,
                           acc[i][2] + bv.z, acc[i][3] + bv.w);
        *reinterpret_cast<f4*>(&C[(size_t)m * N + n]) = o;
    }
}

// Causal un-normalized attention: out[h,t,:] = sum_{s<=t} (q_t . k_s) v_s
// kqv layout (T, 3*DE): k = [0,DE), q = [DE,2DE), v = [2DE,3DE); head h uses cols h*DH..+63
// One block per (q-tile of 64 rows, head). 256 threads, 4x4 micro-tiles.
__global__ __launch_bounds__(256) void attn_kernel(
    const float* __restrict__ kqv, float* __restrict__ attn)
{
    __shared__ float Qt[64][64];   // Qt[d][i]  (transposed: hot loop reads wave-uniform row)
    __shared__ float Kt[64][64];   // Kt[d][j]
    __shared__ float Vs[64][64];   // Vs[j][d]
    __shared__ float Ss[64][64];   // Ss[i][j]
    const int tid = threadIdx.x;
    const int tx = tid & 15, ty = tid >> 4;
    const int h = blockIdx.y;
    const int qt = (int)gridDim.x - 1 - (int)blockIdx.x;  // heavy tiles first
    const int q0 = qt * 64;
    const int LD3 = 3 * DE;
    const int KOFF = h * DH;
    const int QOFF = DE + h * DH;
    const int VOFF = 2 * DE + h * DH;

    // stage Q transposed (once)
    #pragma unroll
    for (int l = 0; l < 4; ++l) {
        const int f = tid + 256 * l;
        const int row = f >> 4, c = (f & 15) * 4;
        f4 qv = *reinterpret_cast<const f4*>(&kqv[(size_t)(q0 + row) * LD3 + QOFF + c]);
        Qt[c + 0][row] = qv.x; Qt[c + 1][row] = qv.y;
        Qt[c + 2][row] = qv.z; Qt[c + 3][row] = qv.w;
    }

    float acc[4][4] = {{0.f}};

    for (int st = 0; st <= qt; ++st) {
        const int s0 = st * 64;
        __syncthreads();   // protect Kt/Vs from previous iteration's readers (also fences Qt at st=0)
        #pragma unroll
        for (int l = 0; l < 4; ++l) {
            const int f = tid + 256 * l;
            const int row = f >> 4, c = (f & 15) * 4;
            const size_t rb = (size_t)(s0 + row) * LD3;
            f4 kv = *reinterpret_cast<const f4*>(&kqv[rb + KOFF + c]);
            Kt[c + 0][row] = kv.x; Kt[c + 1][row] = kv.y;
            Kt[c + 2][row] = kv.z; Kt[c + 3][row] = kv.w;
            f4 vv = *reinterpret_cast<const f4*>(&kqv[rb + VOFF + c]);
            *reinterpret_cast<f4*>(&Vs[row][c]) = vv;
        }
        __syncthreads();

        // phase A: S[i][j] = q_{q0+i} . k_{s0+j};  i = ty*4+ii, j = tx*4+jj
        float s[4][4] = {{0.f}};
        #pragma unroll 8
        for (int d = 0; d < 64; ++d) {
            f4 qv = *reinterpret_cast<const f4*>(&Qt[d][ty * 4]);
            f4 kv = *reinterpret_cast<const f4*>(&Kt[d][tx * 4]);
            const float qa[4] = {qv.x, qv.y, qv.z, qv.w};
            const float ka[4] = {kv.x, kv.y, kv.z, kv.w};
            #pragma unroll
            for (int i = 0; i < 4; ++i)
                #pragma unroll
                for (int j = 0; j < 4; ++j)
                    s[i][j] += qa[i] * ka[j];
        }
        if (st == qt) {   // causal mask on the diagonal tile: keep j <= i
            #pragma unroll
            for (int i = 0; i < 4; ++i)
                #pragma unroll
                for (int j = 0; j < 4; ++j)
                    if (tx * 4 + j > ty * 4 + i) s[i][j] = 0.f;
        }
        #pragma unroll
        for (int i = 0; i < 4; ++i)
            *reinterpret_cast<f4*>(&Ss[ty * 4 + i][tx * 4]) =
                make_float4(s[i][0], s[i][1], s[i][2], s[i][3]);
        __syncthreads();

        // phase B: acc[i][dd] += S[i][j] * V[j][dd];  dd = tx*4+jj
        #pragma unroll 8
        for (int j = 0; j < 64; ++j) {
            f4 vv = *reinterpret_cast<const f4*>(&Vs[j][tx * 4]);
            #pragma unroll
            for (int i = 0; i < 4; ++i) {
                const float sv = Ss[ty * 4 + i][j];
                acc[i][0] += sv * vv.x;
                acc[i][1] += sv * vv.y;
                acc[i][2] += sv * vv.z;
                acc[i][3] += sv * vv.w;
            }
        }
    }

    #pragma unroll
    for (int i = 0; i < 4; ++i) {
        f4 o = make_float4(acc[i][0], acc[i][1], acc[i][2], acc[i][3]);
        *reinterpret_cast<f4*>(&attn[(size_t)(q0 + ty * 4 + i) * DE + h * DH + tx * 4]) = o;
    }
}

extern "C" void kernel_launch(void* const* d_in, const int* in_sizes, int n_in,
                              void* d_out, int out_size, void* d_ws, size_t ws_size,
                              hipStream_t stream) {
    const float* x  = (const float*)d_in[0];
    const float* W1 = (const float*)d_in[1];
    const float* b1 = (const float*)d_in[2];
    const float* W2 = (const float*)d_in[3];
    const float* b2 = (const float*)d_in[4];
    float* out = (float*)d_out;

    float* kqv  = (float*)d_ws;                       // TSEQ x 3*DE fp32 (50.3 MB)
    float* attn = kqv + (size_t)TSEQ * 3 * DE;        // TSEQ x DE fp32 (16.8 MB)

    // kqv = x @ W1 + b1
    gemm_bias_kernel<<<dim3(3 * DE / 64, TSEQ / 64), 256, 0, stream>>>(
        x, W1, b1, kqv, TSEQ, 3 * DE, DE);
    // attn = causal-masked (q k^T) v, per head
    attn_kernel<<<dim3(TSEQ / 64, NH), 256, 0, stream>>>(kqv, attn);
    // out = attn @ W2 + b2
    gemm_bias_kernel<<<dim3(DE / 64, TSEQ / 64), 256, 0, stream>>>(
        attn, W2, b2, out, TSEQ, DE, DE);
}

// Round 2
// 289.699 us; speedup vs baseline: 5.5036x; 5.5036x over previous
//
#include <hip/hip_runtime.h>

#define TSEQ 4096
#define DE   1024
#define NH   16
#define DH   64
#define LD3  3072

typedef float4 f4;
typedef unsigned short u16;
typedef __attribute__((ext_vector_type(8))) short s16x8;   // 8 bf16 (4 VGPRs) MFMA A/B frag
typedef __attribute__((ext_vector_type(4))) float f32x4;   // MFMA C/D frag

// fp32 -> bf16 round-to-nearest-even (finite inputs)
__device__ inline u16 f2bf(float f) {
    unsigned int u = __float_as_uint(f);
    u += 0x7FFF + ((u >> 16) & 1);
    return (u16)(u >> 16);
}

// ---------------- elementwise cast fp32 -> bf16 ----------------
__global__ __launch_bounds__(256) void cast_f32_bf16(const float* __restrict__ in,
                                                     u16* __restrict__ out, int n4) {
    int i = blockIdx.x * 256 + threadIdx.x;
    if (i < n4) {
        f4 v = *reinterpret_cast<const f4*>(&in[(size_t)i * 4]);
        ushort4 o = make_ushort4(f2bf(v.x), f2bf(v.y), f2bf(v.z), f2bf(v.w));
        *reinterpret_cast<ushort4*>(&out[(size_t)i * 4]) = o;
    }
}

// ---------------- tiled transpose+cast: out[c][r] = bf16(in[r][c]) ----------------
// grid (C/64, R/64), 256 threads
__global__ __launch_bounds__(256) void transpose_cast_f32(
    const float* __restrict__ in, u16* __restrict__ out,
    int in_ld, int out_ld) {
    __shared__ u16 Ts[64][65];   // Ts[c][r]; odd-ish stride breaks bank degeneracy
    const int tid = threadIdx.x;
    const int r0 = blockIdx.y * 64, c0 = blockIdx.x * 64;
    #pragma unroll
    for (int l = 0; l < 4; ++l) {
        int f = tid + 256 * l, r = f >> 4, c = (f & 15) * 4;
        f4 v = *reinterpret_cast<const f4*>(&in[(size_t)(r0 + r) * in_ld + c0 + c]);
        Ts[c + 0][r] = f2bf(v.x); Ts[c + 1][r] = f2bf(v.y);
        Ts[c + 2][r] = f2bf(v.z); Ts[c + 3][r] = f2bf(v.w);
    }
    __syncthreads();
    #pragma unroll
    for (int l = 0; l < 2; ++l) {
        int f = tid + 256 * l, r2 = f >> 3, c2 = (f & 7) * 8;
        union { u16 u[8]; f4 v; } pk;
        #pragma unroll
        for (int j = 0; j < 8; ++j) pk.u[j] = Ts[r2][c2 + j];
        *reinterpret_cast<f4*>(&out[(size_t)(c0 + r2) * out_ld + r0 + c2]) = pk.v;
    }
}

// bf16 -> bf16 transpose (for V -> Vtg)
__global__ __launch_bounds__(256) void transpose_bf16(
    const u16* __restrict__ in, u16* __restrict__ out,
    int in_ld, int out_ld) {
    __shared__ u16 Ts[64][65];
    const int tid = threadIdx.x;
    const int r0 = blockIdx.y * 64, c0 = blockIdx.x * 64;
    #pragma unroll
    for (int l = 0; l < 2; ++l) {
        int f = tid + 256 * l, r = f >> 3, c = (f & 7) * 8;
        union { u16 u[8]; f4 v; } pk;
        pk.v = *reinterpret_cast<const f4*>(&in[(size_t)(r0 + r) * in_ld + c0 + c]);
        #pragma unroll
        for (int j = 0; j < 8; ++j) Ts[c + j][r] = pk.u[j];
    }
    __syncthreads();
    #pragma unroll
    for (int l = 0; l < 2; ++l) {
        int f = tid + 256 * l, r2 = f >> 3, c2 = (f & 7) * 8;
        union { u16 u[8]; f4 v; } pk;
        #pragma unroll
        for (int j = 0; j < 8; ++j) pk.u[j] = Ts[r2][c2 + j];
        *reinterpret_cast<f4*>(&out[(size_t)(c0 + r2) * out_ld + r0 + c2]) = pk.v;
    }
}

// ---------------- bf16 MFMA GEMM: C[M][N] = A[M][K] @ Bt[N][K]^T + bias ----------------
// 128x128 tile, BK=32, 256 threads (4 waves, 2x2 of 64x64), 4x4 16x16x32 MFMAs per wave
template<bool OUT_BF16>
__global__ __launch_bounds__(256) void gemm_mfma(
    const u16* __restrict__ A, const u16* __restrict__ Bt,
    const float* __restrict__ bias, void* __restrict__ Cout,
    int M, int N, int K) {
    __shared__ u16 As[128][40];   // stride 40 bf16 = 80B: 16B-aligned rows, ~2-way banks
    __shared__ u16 Bs[128][40];   // Bs[n][k]
    const int tid = threadIdx.x;
    const int m0 = blockIdx.y * 128, n0 = blockIdx.x * 128;
    const int w = tid >> 6, ln = tid & 15, quad = (tid & 63) >> 4;
    const int wm = (w >> 1) * 64, wn = (w & 1) * 64;

    f32x4 acc[4][4];
    #pragma unroll
    for (int i = 0; i < 4; ++i)
        #pragma unroll
        for (int j = 0; j < 4; ++j) acc[i][j] = 0.f;

    for (int k0 = 0; k0 < K; k0 += 32) {
        __syncthreads();   // previous iteration's readers done
        #pragma unroll
        for (int l = 0; l < 2; ++l) {
            int f = tid + 256 * l, row = f >> 2, kc = (f & 3) * 8;
            *reinterpret_cast<f4*>(&As[row][kc]) =
                *reinterpret_cast<const f4*>(&A[(size_t)(m0 + row) * K + k0 + kc]);
            *reinterpret_cast<f4*>(&Bs[row][kc]) =
                *reinterpret_cast<const f4*>(&Bt[(size_t)(n0 + row) * K + k0 + kc]);
        }
        __syncthreads();
        s16x8 a[4], b[4];
        #pragma unroll
        for (int mt = 0; mt < 4; ++mt)
            a[mt] = *reinterpret_cast<const s16x8*>(&As[wm + mt * 16 + ln][quad * 8]);
        #pragma unroll
        for (int nt = 0; nt < 4; ++nt)
            b[nt] = *reinterpret_cast<const s16x8*>(&Bs[wn + nt * 16 + ln][quad * 8]);
        #pragma unroll
        for (int mt = 0; mt < 4; ++mt)
            #pragma unroll
            for (int nt = 0; nt < 4; ++nt)
                acc[mt][nt] = __builtin_amdgcn_mfma_f32_16x16x32_bf16(
                    a[mt], b[nt], acc[mt][nt], 0, 0, 0);
    }

    float bv[4];
    #pragma unroll
    for (int nt = 0; nt < 4; ++nt) bv[nt] = bias[n0 + wn + nt * 16 + ln];
    #pragma unroll
    for (int mt = 0; mt < 4; ++mt)
        #pragma unroll
        for (int nt = 0; nt < 4; ++nt)
            #pragma unroll
            for (int r = 0; r < 4; ++r) {
                // C/D layout: col = lane&15, row = quad*4 + reg  [m89/m91 verified]
                int row = m0 + wm + mt * 16 + quad * 4 + r;
                int col = n0 + wn + nt * 16 + ln;
                float v = acc[mt][nt][r] + bv[nt];
                if (OUT_BF16) ((u16*)Cout)[(size_t)row * N + col] = f2bf(v);
                else          ((float*)Cout)[(size_t)row * N + col] = v;
            }
}

// ---------------- causal retention attention, bf16 MFMA ----------------
// kqvb [T][3072] (k|q|v), Vtg [DE][T] (row = h*64+d), out attnb [T][DE] bf16
__global__ __launch_bounds__(256) void attn_mfma(
    const u16* __restrict__ kqvb, const u16* __restrict__ Vtg,
    u16* __restrict__ attnb) {
    __shared__ u16 Qs[64][72], Ks[64][72], Vt[64][72], Ss[64][72];
    const int tid = threadIdx.x;
    const int h = blockIdx.y;
    const int qt = (int)gridDim.x - 1 - (int)blockIdx.x;   // heavy tiles first
    const int q0 = qt * 64;
    const int w = tid >> 6, ln = tid & 15, quad = (tid & 63) >> 4;

    // stage Q (rows q0..q0+63, d-contiguous)
    #pragma unroll
    for (int l = 0; l < 2; ++l) {
        int f = tid + 256 * l, r = f >> 3, c = (f & 7) * 8;
        *reinterpret_cast<f4*>(&Qs[r][c]) =
            *reinterpret_cast<const f4*>(&kqvb[(size_t)(q0 + r) * LD3 + DE + h * DH + c]);
    }

    f32x4 accO[4];
    #pragma unroll
    for (int nt = 0; nt < 4; ++nt) accO[nt] = 0.f;

    for (int st = 0; st <= qt; ++st) {
        const int s0 = st * 64;
        __syncthreads();   // all waves done reading Ks/Vt (and fences Qs at st=0)
        #pragma unroll
        for (int l = 0; l < 2; ++l) {
            int f = tid + 256 * l, r = f >> 3, c = (f & 7) * 8;
            *reinterpret_cast<f4*>(&Ks[r][c]) =
                *reinterpret_cast<const f4*>(&kqvb[(size_t)(s0 + r) * LD3 + h * DH + c]);
            *reinterpret_cast<f4*>(&Vt[r][c]) =
                *reinterpret_cast<const f4*>(&Vtg[(size_t)(h * DH + r) * TSEQ + s0 + c]);
        }
        __syncthreads();

        // S = Q K^T for this wave's 16 q-rows (m) x 64 s (n)
        s16x8 qa[2];
        #pragma unroll
        for (int kk = 0; kk < 2; ++kk)
            qa[kk] = *reinterpret_cast<const s16x8*>(&Qs[w * 16 + ln][kk * 32 + quad * 8]);
        #pragma unroll
        for (int nt = 0; nt < 4; ++nt) {
            f32x4 s;
            s = 0.f;
            #pragma unroll
            for (int kk = 0; kk < 2; ++kk) {
                s16x8 kb = *reinterpret_cast<const s16x8*>(&Ks[nt * 16 + ln][kk * 32 + quad * 8]);
                s = __builtin_amdgcn_mfma_f32_16x16x32_bf16(qa[kk], kb, s, 0, 0, 0);
            }
            if (st == qt) {   // causal: keep s_idx <= q_idx (diagonal tile)
                #pragma unroll
                for (int r = 0; r < 4; ++r)
                    if (nt * 16 + ln > w * 16 + quad * 4 + r) s[r] = 0.f;
            }
            #pragma unroll
            for (int r = 0; r < 4; ++r)
                Ss[w * 16 + quad * 4 + r][nt * 16 + ln] = f2bf(s[r]);
        }
        // Ss rows [w*16, w*16+16) are wave-private: same-wave LDS ordering suffices
        s16x8 sa[2];
        #pragma unroll
        for (int kk = 0; kk < 2; ++kk)
            sa[kk] = *reinterpret_cast<const s16x8*>(&Ss[w * 16 + ln][kk * 32 + quad * 8]);
        #pragma unroll
        for (int nt = 0; nt < 4; ++nt)
            #pragma unroll
            for (int kk = 0; kk < 2; ++kk) {
                s16x8 vb = *reinterpret_cast<const s16x8*>(&Vt[nt * 16 + ln][kk * 32 + quad * 8]);
                accO[nt] = __builtin_amdgcn_mfma_f32_16x16x32_bf16(sa[kk], vb, accO[nt], 0, 0, 0);
            }
    }

    #pragma unroll
    for (int nt = 0; nt < 4; ++nt)
        #pragma unroll
        for (int r = 0; r < 4; ++r)
            attnb[(size_t)(q0 + w * 16 + quad * 4 + r) * DE + h * DH + nt * 16 + ln] =
                f2bf(accO[nt][r]);
}

extern "C" void kernel_launch(void* const* d_in, const int* in_sizes, int n_in,
                              void* d_out, int out_size, void* d_ws, size_t ws_size,
                              hipStream_t stream) {
    const float* x  = (const float*)d_in[0];
    const float* W1 = (const float*)d_in[1];
    const float* b1 = (const float*)d_in[2];
    const float* W2 = (const float*)d_in[3];
    const float* b2 = (const float*)d_in[4];
    float* out = (float*)d_out;

    u16* xb    = (u16*)d_ws;                       // [4096][1024]
    u16* W1t   = xb    + (size_t)TSEQ * DE;        // [3072][1024]
    u16* W2t   = W1t   + (size_t)LD3 * DE;         // [1024][1024]
    u16* kqvb  = W2t   + (size_t)DE * DE;          // [4096][3072]
    u16* Vtg   = kqvb  + (size_t)TSEQ * LD3;       // [1024][4096]
    u16* attnb = Vtg   + (size_t)DE * TSEQ;        // [4096][1024]

    cast_f32_bf16<<<(TSEQ * DE / 4 + 255) / 256, 256, 0, stream>>>(x, xb, TSEQ * DE / 4);
    transpose_cast_f32<<<dim3(LD3 / 64, DE / 64), 256, 0, stream>>>(W1, W1t, LD3, DE);
    transpose_cast_f32<<<dim3(DE / 64, DE / 64), 256, 0, stream>>>(W2, W2t, DE, DE);

    gemm_mfma<true><<<dim3(LD3 / 128, TSEQ / 128), 256, 0, stream>>>(
        xb, W1t, b1, kqvb, TSEQ, LD3, DE);

    transpose_bf16<<<dim3(DE / 64, TSEQ / 64), 256, 0, stream>>>(
        kqvb + 2 * DE, Vtg, LD3, TSEQ);

    attn_mfma<<<dim3(TSEQ / 64, NH), 256, 0, stream>>>(kqvb, Vtg, attnb);

    gemm_mfma<false><<<dim3(DE / 128, TSEQ / 128), 256, 0, stream>>>(
        attnb, W2t, b2, out, TSEQ, DE, DE);
}

// Round 3
// 265.523 us; speedup vs baseline: 6.0048x; 1.0911x over previous
//
#include <hip/hip_runtime.h>
#include <hip/hip_bf16.h>

#define TSEQ 4096
#define DE   1024
#define NH   16
#define DH   64
#define LD3  3072

typedef float4 f4;
typedef unsigned short u16;
typedef __attribute__((ext_vector_type(8))) short s16x8;   // 8 bf16 MFMA A/B frag
typedef __attribute__((ext_vector_type(4))) float f32x4;   // MFMA C/D frag

__device__ inline u16 f2bf(float f) {
    unsigned int u = __float_as_uint(f);
    u += 0x7FFF + ((u >> 16) & 1);
    return (u16)(u >> 16);
}

// ---------------- elementwise cast fp32 -> bf16 ----------------
__global__ __launch_bounds__(256) void cast_f32_bf16(const float* __restrict__ in,
                                                     u16* __restrict__ out, int n4) {
    int i = blockIdx.x * 256 + threadIdx.x;
    if (i < n4) {
        f4 v = *reinterpret_cast<const f4*>(&in[(size_t)i * 4]);
        ushort4 o = make_ushort4(f2bf(v.x), f2bf(v.y), f2bf(v.z), f2bf(v.w));
        *reinterpret_cast<ushort4*>(&out[(size_t)i * 4]) = o;
    }
}

// ---------------- tiled transpose+cast fp32 -> bf16 ----------------
__global__ __launch_bounds__(256) void transpose_cast_f32(
    const float* __restrict__ in, u16* __restrict__ out,
    int in_ld, int out_ld) {
    __shared__ u16 Ts[64][65];
    const int tid = threadIdx.x;
    const int r0 = blockIdx.y * 64, c0 = blockIdx.x * 64;
    #pragma unroll
    for (int l = 0; l < 4; ++l) {
        int f = tid + 256 * l, r = f >> 4, c = (f & 15) * 4;
        f4 v = *reinterpret_cast<const f4*>(&in[(size_t)(r0 + r) * in_ld + c0 + c]);
        Ts[c + 0][r] = f2bf(v.x); Ts[c + 1][r] = f2bf(v.y);
        Ts[c + 2][r] = f2bf(v.z); Ts[c + 3][r] = f2bf(v.w);
    }
    __syncthreads();
    #pragma unroll
    for (int l = 0; l < 2; ++l) {
        int f = tid + 256 * l, r2 = f >> 3, c2 = (f & 7) * 8;
        union { u16 u[8]; f4 v; } pk;
        #pragma unroll
        for (int j = 0; j < 8; ++j) pk.u[j] = Ts[r2][c2 + j];
        *reinterpret_cast<f4*>(&out[(size_t)(c0 + r2) * out_ld + r0 + c2]) = pk.v;
    }
}

// bf16 -> bf16 transpose (V -> Vtg)
__global__ __launch_bounds__(256) void transpose_bf16(
    const u16* __restrict__ in, u16* __restrict__ out,
    int in_ld, int out_ld) {
    __shared__ u16 Ts[64][65];
    const int tid = threadIdx.x;
    const int r0 = blockIdx.y * 64, c0 = blockIdx.x * 64;
    #pragma unroll
    for (int l = 0; l < 2; ++l) {
        int f = tid + 256 * l, r = f >> 3, c = (f & 7) * 8;
        union { u16 u[8]; f4 v; } pk;
        pk.v = *reinterpret_cast<const f4*>(&in[(size_t)(r0 + r) * in_ld + c0 + c]);
        #pragma unroll
        for (int j = 0; j < 8; ++j) Ts[c + j][r] = pk.u[j];
    }
    __syncthreads();
    #pragma unroll
    for (int l = 0; l < 2; ++l) {
        int f = tid + 256 * l, r2 = f >> 3, c2 = (f & 7) * 8;
        union { u16 u[8]; f4 v; } pk;
        #pragma unroll
        for (int j = 0; j < 8; ++j) pk.u[j] = Ts[r2][c2 + j];
        *reinterpret_cast<f4*>(&out[(size_t)(c0 + r2) * out_ld + r0 + c2]) = pk.v;
    }
}

// ---------------- bf16 MFMA GEMM (unchanged from R2) ----------------
template<bool OUT_BF16>
__global__ __launch_bounds__(256) void gemm_mfma(
    const u16* __restrict__ A, const u16* __restrict__ Bt,
    const float* __restrict__ bias, void* __restrict__ Cout,
    int M, int N, int K) {
    __shared__ u16 As[128][40];
    __shared__ u16 Bs[128][40];
    const int tid = threadIdx.x;
    const int m0 = blockIdx.y * 128, n0 = blockIdx.x * 128;
    const int w = tid >> 6, ln = tid & 15, quad = (tid & 63) >> 4;
    const int wm = (w >> 1) * 64, wn = (w & 1) * 64;

    f32x4 acc[4][4];
    #pragma unroll
    for (int i = 0; i < 4; ++i)
        #pragma unroll
        for (int j = 0; j < 4; ++j) acc[i][j] = 0.f;

    for (int k0 = 0; k0 < K; k0 += 32) {
        __syncthreads();
        #pragma unroll
        for (int l = 0; l < 2; ++l) {
            int f = tid + 256 * l, row = f >> 2, kc = (f & 3) * 8;
            *reinterpret_cast<f4*>(&As[row][kc]) =
                *reinterpret_cast<const f4*>(&A[(size_t)(m0 + row) * K + k0 + kc]);
            *reinterpret_cast<f4*>(&Bs[row][kc]) =
                *reinterpret_cast<const f4*>(&Bt[(size_t)(n0 + row) * K + k0 + kc]);
        }
        __syncthreads();
        s16x8 a[4], b[4];
        #pragma unroll
        for (int mt = 0; mt < 4; ++mt)
            a[mt] = *reinterpret_cast<const s16x8*>(&As[wm + mt * 16 + ln][quad * 8]);
        #pragma unroll
        for (int nt = 0; nt < 4; ++nt)
            b[nt] = *reinterpret_cast<const s16x8*>(&Bs[wn + nt * 16 + ln][quad * 8]);
        #pragma unroll
        for (int mt = 0; mt < 4; ++mt)
            #pragma unroll
            for (int nt = 0; nt < 4; ++nt)
                acc[mt][nt] = __builtin_amdgcn_mfma_f32_16x16x32_bf16(
                    a[mt], b[nt], acc[mt][nt], 0, 0, 0);
    }

    float bv[4];
    #pragma unroll
    for (int nt = 0; nt < 4; ++nt) bv[nt] = bias[n0 + wn + nt * 16 + ln];
    #pragma unroll
    for (int mt = 0; mt < 4; ++mt)
        #pragma unroll
        for (int nt = 0; nt < 4; ++nt)
            #pragma unroll
            for (int r = 0; r < 4; ++r) {
                int row = m0 + wm + mt * 16 + quad * 4 + r;
                int col = n0 + wn + nt * 16 + ln;
                float v = acc[mt][nt][r] + bv[nt];
                if (OUT_BF16) ((u16*)Cout)[(size_t)row * N + col] = f2bf(v);
                else          ((float*)Cout)[(size_t)row * N + col] = v;
            }
}

// ---------------- causal retention attention: wave-owns-s-tile ----------------
// Per block: 64 q-rows x 1 head. 4 waves, wave w handles s-tiles st = w, w+4, ...
// K,Q,V fragments load DIRECTLY from global (64B-segment coalesced, L2-resident);
// LDS used only for the wave-private S^T->S round trip + final O reduction.
// No __syncthreads in the main loop.
__global__ __launch_bounds__(256, 2) void attn_mfma(
    const u16* __restrict__ kqvb, const u16* __restrict__ Vtg,
    u16* __restrict__ attnb) {
    __shared__ u16 Ss[4][64][72];   // per-wave S buffer [q][s], stride 72 (144B, 16B-aligned)
    const int tid = threadIdx.x;
    const int w = tid >> 6, ln = tid & 15, quad = (tid & 63) >> 4;
    const int h = blockIdx.y;
    const int qt = (int)gridDim.x - 1 - (int)blockIdx.x;   // heavy tiles first
    const int q0 = qt * 64;

    const u16* Kg = kqvb + h * DH;                 // K[t][d] rows of 3072
    const u16* Qg = kqvb + DE + h * DH;            // Q[t][d]
    const u16* Vg = Vtg + (size_t)(h * DH) * TSEQ; // V^T[d][s] rows of 4096

    // Q B-fragments, register-persistent: qf[nt][kk] covers q rows nt*16, d kk*32
    s16x8 qf[4][2];
    #pragma unroll
    for (int nt = 0; nt < 4; ++nt)
        #pragma unroll
        for (int kk = 0; kk < 2; ++kk)
            qf[nt][kk] = *reinterpret_cast<const s16x8*>(
                &Qg[(size_t)(q0 + nt * 16 + ln) * LD3 + kk * 32 + quad * 8]);

    f32x4 accO[4][4];   // [mt = q sub-tile][nt = d sub-tile]
    #pragma unroll
    for (int i = 0; i < 4; ++i)
        #pragma unroll
        for (int j = 0; j < 4; ++j) accO[i][j] = 0.f;

    for (int st = w; st <= qt; st += 4) {
        const int s0 = st * 64;
        const bool diag = (st == qt);

        // ---- phase A: S^T = K Q^T, write S[q][s] to wave-private LDS ----
        #pragma unroll
        for (int half = 0; half < 2; ++half) {
            s16x8 kf[2][2];
            #pragma unroll
            for (int m2 = 0; m2 < 2; ++m2)
                #pragma unroll
                for (int kk = 0; kk < 2; ++kk)
                    kf[m2][kk] = *reinterpret_cast<const s16x8*>(
                        &Kg[(size_t)(s0 + (half * 2 + m2) * 16 + ln) * LD3 + kk * 32 + quad * 8]);
            #pragma unroll
            for (int m2 = 0; m2 < 2; ++m2) {
                const int mt = half * 2 + m2;
                #pragma unroll
                for (int nt = 0; nt < 4; ++nt) {
                    f32x4 s;
                    s = 0.f;
                    #pragma unroll
                    for (int kk = 0; kk < 2; ++kk)
                        s = __builtin_amdgcn_mfma_f32_16x16x32_bf16(kf[m2][kk], qf[nt][kk], s, 0, 0, 0);
                    if (diag) {   // zero where s > q  (s = mt*16+quad*4+r, q = nt*16+ln)
                        #pragma unroll
                        for (int r = 0; r < 4; ++r)
                            if (mt * 16 + quad * 4 + r > nt * 16 + ln) s[r] = 0.f;
                    }
                    // pack 4 bf16, one b64 write: Ss[w][nt*16+ln][mt*16+quad*4 .. +3]
                    __hip_bfloat162 p0 = __float22bfloat162_rn(make_float2(s[0], s[1]));
                    __hip_bfloat162 p1 = __float22bfloat162_rn(make_float2(s[2], s[3]));
                    uint2 pk = make_uint2(*reinterpret_cast<unsigned int*>(&p0),
                                          *reinterpret_cast<unsigned int*>(&p1));
                    *reinterpret_cast<uint2*>(&Ss[w][nt * 16 + ln][mt * 16 + quad * 4]) = pk;
                }
            }
        }

        // ---- phase B: O += S V  (A = S from LDS, B = V^T direct from global) ----
        s16x8 sf[4][2];
        #pragma unroll
        for (int mt = 0; mt < 4; ++mt)
            #pragma unroll
            for (int kk = 0; kk < 2; ++kk)
                sf[mt][kk] = *reinterpret_cast<const s16x8*>(
                    &Ss[w][mt * 16 + ln][kk * 32 + quad * 8]);
        #pragma unroll
        for (int nt = 0; nt < 4; ++nt)
            #pragma unroll
            for (int kk = 0; kk < 2; ++kk) {
                s16x8 vf = *reinterpret_cast<const s16x8*>(
                    &Vg[(size_t)(nt * 16 + ln) * TSEQ + s0 + kk * 32 + quad * 8]);
                #pragma unroll
                for (int mt = 0; mt < 4; ++mt)
                    accO[mt][nt] = __builtin_amdgcn_mfma_f32_16x16x32_bf16(
                        sf[mt][kk], vf, accO[mt][nt], 0, 0, 0);
            }
    }

    // ---- cross-wave fp32 reduction of accO through LDS, 2 rounds of 32 q-rows ----
    #pragma unroll
    for (int g = 0; g < 2; ++g) {
        __syncthreads();   // previous round / main loop done with Ss
        float* Rf = (float*)&Ss[w][0][0];   // region: [32][68] floats = 8704 B <= 9216
        #pragma unroll
        for (int m2 = 0; m2 < 2; ++m2)
            #pragma unroll
            for (int nt = 0; nt < 4; ++nt)
                #pragma unroll
                for (int r = 0; r < 4; ++r)
                    Rf[(m2 * 16 + quad * 4 + r) * 68 + nt * 16 + ln] = accO[g * 2 + m2][nt][r];
        __syncthreads();
        const float* R0 = (const float*)&Ss[0][0][0];
        const float* R1 = (const float*)&Ss[1][0][0];
        const float* R2 = (const float*)&Ss[2][0][0];
        const float* R3 = (const float*)&Ss[3][0][0];
        #pragma unroll
        for (int j = 0; j < 2; ++j) {
            int i = tid * 8 + j * 4;           // 2048 floats this round
            int qr = i >> 6, c = i & 63;
            int a = qr * 68 + c;
            f4 v0 = *reinterpret_cast<const f4*>(&R0[a]);
            f4 v1 = *reinterpret_cast<const f4*>(&R1[a]);
            f4 v2 = *reinterpret_cast<const f4*>(&R2[a]);
            f4 v3 = *reinterpret_cast<const f4*>(&R3[a]);
            float s0 = v0.x + v1.x + v2.x + v3.x;
            float s1 = v0.y + v1.y + v2.y + v3.y;
            float s2 = v0.z + v1.z + v2.z + v3.z;
            float s3 = v0.w + v1.w + v2.w + v3.w;
            __hip_bfloat162 p0 = __float22bfloat162_rn(make_float2(s0, s1));
            __hip_bfloat162 p1 = __float22bfloat162_rn(make_float2(s2, s3));
            uint2 pk = make_uint2(*reinterpret_cast<unsigned int*>(&p0),
                                  *reinterpret_cast<unsigned int*>(&p1));
            *reinterpret_cast<uint2*>(
                &attnb[(size_t)(q0 + g * 32 + qr) * DE + h * DH + c]) = pk;
        }
    }
}

extern "C" void kernel_launch(void* const* d_in, const int* in_sizes, int n_in,
                              void* d_out, int out_size, void* d_ws, size_t ws_size,
                              hipStream_t stream) {
    const float* x  = (const float*)d_in[0];
    const float* W1 = (const float*)d_in[1];
    const float* b1 = (const float*)d_in[2];
    const float* W2 = (const float*)d_in[3];
    const float* b2 = (const float*)d_in[4];
    float* out = (float*)d_out;

    u16* xb    = (u16*)d_ws;                       // [4096][1024]
    u16* W1t   = xb    + (size_t)TSEQ * DE;        // [3072][1024]
    u16* W2t   = W1t   + (size_t)LD3 * DE;         // [1024][1024]
    u16* kqvb  = W2t   + (size_t)DE * DE;          // [4096][3072]
    u16* Vtg   = kqvb  + (size_t)TSEQ * LD3;       // [1024][4096]
    u16* attnb = Vtg   + (size_t)DE * TSEQ;        // [4096][1024]

    cast_f32_bf16<<<(TSEQ * DE / 4 + 255) / 256, 256, 0, stream>>>(x, xb, TSEQ * DE / 4);
    transpose_cast_f32<<<dim3(LD3 / 64, DE / 64), 256, 0, stream>>>(W1, W1t, LD3, DE);
    transpose_cast_f32<<<dim3(DE / 64, DE / 64), 256, 0, stream>>>(W2, W2t, DE, DE);

    gemm_mfma<true><<<dim3(LD3 / 128, TSEQ / 128), 256, 0, stream>>>(
        xb, W1t, b1, kqvb, TSEQ, LD3, DE);

    transpose_bf16<<<dim3(DE / 64, TSEQ / 64), 256, 0, stream>>>(
        kqvb + 2 * DE, Vtg, LD3, TSEQ);

    attn_mfma<<<dim3(TSEQ / 64, NH), 256, 0, stream>>>(kqvb, Vtg, attnb);

    gemm_mfma<false><<<dim3(DE / 128, TSEQ / 128), 256, 0, stream>>>(
        attnb, W2t, b2, out, TSEQ, DE, DE);
}

// Round 4
// 256.060 us; speedup vs baseline: 6.2267x; 1.0370x over previous
//
#include <hip/hip_runtime.h>
#include <hip/hip_bf16.h>

#define TSEQ 4096
#define DE   1024
#define NH   16
#define DH   64
#define LD3  3072

typedef float4 f4;
typedef unsigned short u16;
typedef __attribute__((ext_vector_type(8))) short s16x8;   // 8 bf16 MFMA A/B frag
typedef __attribute__((ext_vector_type(4))) float f32x4;   // MFMA C/D frag

__device__ inline u16 f2bf(float f) {
    unsigned int u = __float_as_uint(f);
    u += 0x7FFF + ((u >> 16) & 1);
    return (u16)(u >> 16);
}

__device__ inline void gl_lds16(const void* g, void* l) {
    __builtin_amdgcn_global_load_lds(
        (const __attribute__((address_space(1))) void*)g,
        (__attribute__((address_space(3))) void*)l, 16, 0, 0);
}

// ---------------- elementwise cast fp32 -> bf16 ----------------
__global__ __launch_bounds__(256) void cast_f32_bf16(const float* __restrict__ in,
                                                     u16* __restrict__ out, int n4) {
    int i = blockIdx.x * 256 + threadIdx.x;
    if (i < n4) {
        f4 v = *reinterpret_cast<const f4*>(&in[(size_t)i * 4]);
        ushort4 o = make_ushort4(f2bf(v.x), f2bf(v.y), f2bf(v.z), f2bf(v.w));
        *reinterpret_cast<ushort4*>(&out[(size_t)i * 4]) = o;
    }
}

// ---------------- tiled transpose+cast fp32 -> bf16 ----------------
__global__ __launch_bounds__(256) void transpose_cast_f32(
    const float* __restrict__ in, u16* __restrict__ out,
    int in_ld, int out_ld) {
    __shared__ u16 Ts[64][65];
    const int tid = threadIdx.x;
    const int r0 = blockIdx.y * 64, c0 = blockIdx.x * 64;
    #pragma unroll
    for (int l = 0; l < 4; ++l) {
        int f = tid + 256 * l, r = f >> 4, c = (f & 15) * 4;
        f4 v = *reinterpret_cast<const f4*>(&in[(size_t)(r0 + r) * in_ld + c0 + c]);
        Ts[c + 0][r] = f2bf(v.x); Ts[c + 1][r] = f2bf(v.y);
        Ts[c + 2][r] = f2bf(v.z); Ts[c + 3][r] = f2bf(v.w);
    }
    __syncthreads();
    #pragma unroll
    for (int l = 0; l < 2; ++l) {
        int f = tid + 256 * l, r2 = f >> 3, c2 = (f & 7) * 8;
        union { u16 u[8]; f4 v; } pk;
        #pragma unroll
        for (int j = 0; j < 8; ++j) pk.u[j] = Ts[r2][c2 + j];
        *reinterpret_cast<f4*>(&out[(size_t)(c0 + r2) * out_ld + r0 + c2]) = pk.v;
    }
}

// bf16 -> bf16 transpose (V -> Vtg)
__global__ __launch_bounds__(256) void transpose_bf16(
    const u16* __restrict__ in, u16* __restrict__ out,
    int in_ld, int out_ld) {
    __shared__ u16 Ts[64][65];
    const int tid = threadIdx.x;
    const int r0 = blockIdx.y * 64, c0 = blockIdx.x * 64;
    #pragma unroll
    for (int l = 0; l < 2; ++l) {
        int f = tid + 256 * l, r = f >> 3, c = (f & 7) * 8;
        union { u16 u[8]; f4 v; } pk;
        pk.v = *reinterpret_cast<const f4*>(&in[(size_t)(r0 + r) * in_ld + c0 + c]);
        #pragma unroll
        for (int j = 0; j < 8; ++j) Ts[c + j][r] = pk.u[j];
    }
    __syncthreads();
    #pragma unroll
    for (int l = 0; l < 2; ++l) {
        int f = tid + 256 * l, r2 = f >> 3, c2 = (f & 7) * 8;
        union { u16 u[8]; f4 v; } pk;
        #pragma unroll
        for (int j = 0; j < 8; ++j) pk.u[j] = Ts[r2][c2 + j];
        *reinterpret_cast<f4*>(&out[(size_t)(c0 + r2) * out_ld + r0 + c2]) = pk.v;
    }
}

// ---------------- bf16 MFMA GEMM, m97-style global_load_lds staging ----------------
// C[M][N] = A[M][K] @ Bt[N][K]^T + bias. 128x128 tile, BK=32, 256 threads.
// LDS tiles UNPADDED [128][32] (global_load_lds needs contiguous lane order).
template<bool OUT_BF16>
__global__ __launch_bounds__(256) void gemm_mfma(
    const u16* __restrict__ A, const u16* __restrict__ Bt,
    const float* __restrict__ bias, void* __restrict__ Cout,
    int M, int N, int K) {
    __shared__ u16 As[128][32];
    __shared__ u16 Bs[128][32];
    const int tid = threadIdx.x;
    const int m0 = blockIdx.y * 128, n0 = blockIdx.x * 128;
    const int w = tid >> 6, lid = tid & 63, ln = tid & 15, quad = (tid & 63) >> 4;
    const int wm = (w >> 1) * 64, wn = (w & 1) * 64;
    const int srow = lid >> 2, scol = (lid & 3) * 8;   // lane's slot in a 16-row chunk

    f32x4 acc[4][4];
    #pragma unroll
    for (int i = 0; i < 4; ++i)
        #pragma unroll
        for (int j = 0; j < 4; ++j) acc[i][j] = 0.f;

    for (int k0 = 0; k0 < K; k0 += 32) {
        __syncthreads();   // previous iteration's readers done
        #pragma unroll
        for (int i = 0; i < 2; ++i) {
            const int rb = w * 16 + i * 64;   // wave-uniform 16-row chunk base
            gl_lds16(&A[(size_t)(m0 + rb + srow) * K + k0 + scol], &As[rb][0]);
            gl_lds16(&Bt[(size_t)(n0 + rb + srow) * K + k0 + scol], &Bs[rb][0]);
        }
        __syncthreads();   // vmcnt(0) drain before barrier makes LDS data visible
        s16x8 a[4], b[4];
        #pragma unroll
        for (int mt = 0; mt < 4; ++mt)
            a[mt] = *reinterpret_cast<const s16x8*>(&As[wm + mt * 16 + ln][quad * 8]);
        #pragma unroll
        for (int nt = 0; nt < 4; ++nt)
            b[nt] = *reinterpret_cast<const s16x8*>(&Bs[wn + nt * 16 + ln][quad * 8]);
        #pragma unroll
        for (int mt = 0; mt < 4; ++mt)
            #pragma unroll
            for (int nt = 0; nt < 4; ++nt)
                acc[mt][nt] = __builtin_amdgcn_mfma_f32_16x16x32_bf16(
                    a[mt], b[nt], acc[mt][nt], 0, 0, 0);
    }

    float bv[4];
    #pragma unroll
    for (int nt = 0; nt < 4; ++nt) bv[nt] = bias[n0 + wn + nt * 16 + ln];
    #pragma unroll
    for (int mt = 0; mt < 4; ++mt)
        #pragma unroll
        for (int nt = 0; nt < 4; ++nt)
            #pragma unroll
            for (int r = 0; r < 4; ++r) {
                int row = m0 + wm + mt * 16 + quad * 4 + r;
                int col = n0 + wn + nt * 16 + ln;
                float v = acc[mt][nt][r] + bv[nt];
                if (OUT_BF16) ((u16*)Cout)[(size_t)row * N + col] = f2bf(v);
                else          ((float*)Cout)[(size_t)row * N + col] = v;
            }
}

// ---------------- causal retention attention: 128-q block, wave-owns-s-tile ----------------
// Block = 128 q-rows x 1 head; wave w handles s-tiles st = w, w+4, ...
// Per wave-s-tile: 128 MFMA vs 32 global loads. O accumulates in registers;
// cross-wave fp32 reduction at the end. No barriers in the main loop.
__global__ __launch_bounds__(256, 2) void attn_mfma(
    const u16* __restrict__ kqvb, const u16* __restrict__ Vtg,
    u16* __restrict__ attnb) {
    __shared__ u16 Ss[4][128][72];   // per-wave S[q][s] buffer (73.7 KB; 2 blocks/CU)
    const int tid = threadIdx.x;
    const int w = tid >> 6, ln = tid & 15, quad = (tid & 63) >> 4;
    const int h = blockIdx.y;
    const int qb = (int)gridDim.x - 1 - (int)blockIdx.x;   // heavy blocks first
    const int q0 = qb * 128;
    const int nst = 2 * qb + 2;   // s-tiles needed: s <= q0+127  ->  st*64 < q0+128

    const u16* Kg = kqvb + h * DH;                 // K[t][d], row stride 3072
    const u16* Qg = kqvb + DE + h * DH;            // Q[t][d]
    const u16* Vg = Vtg + (size_t)(h * DH) * TSEQ; // V^T[d][s], row stride 4096

    f32x4 accO[8][4];   // [q sub-tile][d sub-tile]
    #pragma unroll
    for (int i = 0; i < 8; ++i)
        #pragma unroll
        for (int j = 0; j < 4; ++j) accO[i][j] = 0.f;

    for (int st = w; st < nst; st += 4) {
        const int s0 = st * 64;
        const bool diag = (s0 >= q0);   // partially/fully masked tile

        // K fragments for this s-tile (held across phase A)
        s16x8 kf[4][2];
        #pragma unroll
        for (int mt = 0; mt < 4; ++mt)
            #pragma unroll
            for (int kk = 0; kk < 2; ++kk)
                kf[mt][kk] = *reinterpret_cast<const s16x8*>(
                    &Kg[(size_t)(s0 + mt * 16 + ln) * LD3 + kk * 32 + quad * 8]);

        // ---- phase A: S^T = K Q^T -> wave-private LDS as S[q][s] ----
        #pragma unroll
        for (int nt = 0; nt < 8; ++nt) {
            const size_t qrow = (size_t)(q0 + nt * 16 + ln) * LD3;
            s16x8 qf0 = *reinterpret_cast<const s16x8*>(&Qg[qrow + quad * 8]);
            s16x8 qf1 = *reinterpret_cast<const s16x8*>(&Qg[qrow + 32 + quad * 8]);
            #pragma unroll
            for (int mt = 0; mt < 4; ++mt) {
                f32x4 s;
                s = 0.f;
                s = __builtin_amdgcn_mfma_f32_16x16x32_bf16(kf[mt][0], qf0, s, 0, 0, 0);
                s = __builtin_amdgcn_mfma_f32_16x16x32_bf16(kf[mt][1], qf1, s, 0, 0, 0);
                if (diag) {   // zero where s_g > q_g
                    #pragma unroll
                    for (int r = 0; r < 4; ++r)
                        if (s0 + mt * 16 + quad * 4 + r > q0 + nt * 16 + ln) s[r] = 0.f;
                }
                __hip_bfloat162 p0 = __float22bfloat162_rn(make_float2(s[0], s[1]));
                __hip_bfloat162 p1 = __float22bfloat162_rn(make_float2(s[2], s[3]));
                uint2 pk = make_uint2(*reinterpret_cast<unsigned int*>(&p0),
                                      *reinterpret_cast<unsigned int*>(&p1));
                *reinterpret_cast<uint2*>(&Ss[w][nt * 16 + ln][mt * 16 + quad * 4]) = pk;
            }
        }

        // ---- phase B: O += S V ----
        s16x8 vf[4][2];
        #pragma unroll
        for (int nt = 0; nt < 4; ++nt)
            #pragma unroll
            for (int kk = 0; kk < 2; ++kk)
                vf[nt][kk] = *reinterpret_cast<const s16x8*>(
                    &Vg[(size_t)(nt * 16 + ln) * TSEQ + s0 + kk * 32 + quad * 8]);
        #pragma unroll
        for (int mt = 0; mt < 8; ++mt) {
            s16x8 sf0 = *reinterpret_cast<const s16x8*>(&Ss[w][mt * 16 + ln][quad * 8]);
            s16x8 sf1 = *reinterpret_cast<const s16x8*>(&Ss[w][mt * 16 + ln][32 + quad * 8]);
            #pragma unroll
            for (int nt = 0; nt < 4; ++nt) {
                accO[mt][nt] = __builtin_amdgcn_mfma_f32_16x16x32_bf16(
                    sf0, vf[nt][0], accO[mt][nt], 0, 0, 0);
                accO[mt][nt] = __builtin_amdgcn_mfma_f32_16x16x32_bf16(
                    sf1, vf[nt][1], accO[mt][nt], 0, 0, 0);
            }
        }
    }

    // ---- cross-wave fp32 reduction, 4 rounds of 32 q-rows ----
    #pragma unroll
    for (int g = 0; g < 4; ++g) {
        __syncthreads();   // main loop / previous round done with Ss
        float* Rf = (float*)&Ss[w][0][0];   // [32][68] floats = 8704 B (region is 18432 B)
        #pragma unroll
        for (int m2 = 0; m2 < 2; ++m2)
            #pragma unroll
            for (int nt = 0; nt < 4; ++nt)
                #pragma unroll
                for (int r = 0; r < 4; ++r)
                    Rf[(m2 * 16 + quad * 4 + r) * 68 + nt * 16 + ln] = accO[g * 2 + m2][nt][r];
        __syncthreads();
        const float* R0 = (const float*)&Ss[0][0][0];
        const float* R1 = (const float*)&Ss[1][0][0];
        const float* R2 = (const float*)&Ss[2][0][0];
        const float* R3 = (const float*)&Ss[3][0][0];
        #pragma unroll
        for (int j = 0; j < 2; ++j) {
            int i = tid * 8 + j * 4;
            int qr = i >> 6, c = i & 63;
            int a = qr * 68 + c;
            f4 v0 = *reinterpret_cast<const f4*>(&R0[a]);
            f4 v1 = *reinterpret_cast<const f4*>(&R1[a]);
            f4 v2 = *reinterpret_cast<const f4*>(&R2[a]);
            f4 v3 = *reinterpret_cast<const f4*>(&R3[a]);
            float s0 = v0.x + v1.x + v2.x + v3.x;
            float s1 = v0.y + v1.y + v2.y + v3.y;
            float s2 = v0.z + v1.z + v2.z + v3.z;
            float s3 = v0.w + v1.w + v2.w + v3.w;
            __hip_bfloat162 p0 = __float22bfloat162_rn(make_float2(s0, s1));
            __hip_bfloat162 p1 = __float22bfloat162_rn(make_float2(s2, s3));
            uint2 pk = make_uint2(*reinterpret_cast<unsigned int*>(&p0),
                                  *reinterpret_cast<unsigned int*>(&p1));
            *reinterpret_cast<uint2*>(
                &attnb[(size_t)(q0 + g * 32 + qr) * DE + h * DH + c]) = pk;
        }
    }
}

extern "C" void kernel_launch(void* const* d_in, const int* in_sizes, int n_in,
                              void* d_out, int out_size, void* d_ws, size_t ws_size,
                              hipStream_t stream) {
    const float* x  = (const float*)d_in[0];
    const float* W1 = (const float*)d_in[1];
    const float* b1 = (const float*)d_in[2];
    const float* W2 = (const float*)d_in[3];
    const float* b2 = (const float*)d_in[4];
    float* out = (float*)d_out;

    u16* xb    = (u16*)d_ws;                       // [4096][1024]
    u16* W1t   = xb    + (size_t)TSEQ * DE;        // [3072][1024]
    u16* W2t   = W1t   + (size_t)LD3 * DE;         // [1024][1024]
    u16* kqvb  = W2t   + (size_t)DE * DE;          // [4096][3072]
    u16* Vtg   = kqvb  + (size_t)TSEQ * LD3;       // [1024][4096]
    u16* attnb = Vtg   + (size_t)DE * TSEQ;        // [4096][1024]

    cast_f32_bf16<<<(TSEQ * DE / 4 + 255) / 256, 256, 0, stream>>>(x, xb, TSEQ * DE / 4);
    transpose_cast_f32<<<dim3(LD3 / 64, DE / 64), 256, 0, stream>>>(W1, W1t, LD3, DE);
    transpose_cast_f32<<<dim3(DE / 64, DE / 64), 256, 0, stream>>>(W2, W2t, DE, DE);

    gemm_mfma<true><<<dim3(LD3 / 128, TSEQ / 128), 256, 0, stream>>>(
        xb, W1t, b1, kqvb, TSEQ, LD3, DE);

    transpose_bf16<<<dim3(DE / 64, TSEQ / 64), 256, 0, stream>>>(
        kqvb + 2 * DE, Vtg, LD3, TSEQ);

    attn_mfma<<<dim3(TSEQ / 128, NH), 256, 0, stream>>>(kqvb, Vtg, attnb);

    gemm_mfma<false><<<dim3(DE / 128, TSEQ / 128), 256, 0, stream>>>(
        attnb, W2t, b2, out, TSEQ, DE, DE);
}

// Round 5
// 189.245 us; speedup vs baseline: 8.4251x; 1.3531x over previous
//
#include <hip/hip_runtime.h>
#include <hip/hip_bf16.h>

#define TSEQ 4096
#define DE   1024
#define NH   16
#define DH   64
#define LD3  3072
#define NCH  64          // chunks of 64 rows for the linear-attention scan

typedef float4 f4;
typedef unsigned short u16;
typedef __attribute__((ext_vector_type(8))) short s16x8;   // 8 bf16 MFMA A/B frag
typedef __attribute__((ext_vector_type(4))) float f32x4;   // MFMA C/D frag

__device__ inline u16 f2bf(float f) {
    unsigned int u = __float_as_uint(f);
    u += 0x7FFF + ((u >> 16) & 1);
    return (u16)(u >> 16);
}

// ---------------- elementwise cast fp32 -> bf16 ----------------
__global__ __launch_bounds__(256) void cast_f32_bf16(const float* __restrict__ in,
                                                     u16* __restrict__ out, int n4) {
    int i = blockIdx.x * 256 + threadIdx.x;
    if (i < n4) {
        f4 v = *reinterpret_cast<const f4*>(&in[(size_t)i * 4]);
        ushort4 o = make_ushort4(f2bf(v.x), f2bf(v.y), f2bf(v.z), f2bf(v.w));
        *reinterpret_cast<ushort4*>(&out[(size_t)i * 4]) = o;
    }
}

// ---------------- tiled transpose+cast fp32 -> bf16 ----------------
__global__ __launch_bounds__(256) void transpose_cast_f32(
    const float* __restrict__ in, u16* __restrict__ out,
    int in_ld, int out_ld) {
    __shared__ u16 Ts[64][65];
    const int tid = threadIdx.x;
    const int r0 = blockIdx.y * 64, c0 = blockIdx.x * 64;
    #pragma unroll
    for (int l = 0; l < 4; ++l) {
        int f = tid + 256 * l, r = f >> 4, c = (f & 15) * 4;
        f4 v = *reinterpret_cast<const f4*>(&in[(size_t)(r0 + r) * in_ld + c0 + c]);
        Ts[c + 0][r] = f2bf(v.x); Ts[c + 1][r] = f2bf(v.y);
        Ts[c + 2][r] = f2bf(v.z); Ts[c + 3][r] = f2bf(v.w);
    }
    __syncthreads();
    #pragma unroll
    for (int l = 0; l < 2; ++l) {
        int f = tid + 256 * l, r2 = f >> 3, c2 = (f & 7) * 8;
        union { u16 u[8]; f4 v; } pk;
        #pragma unroll
        for (int j = 0; j < 8; ++j) pk.u[j] = Ts[r2][c2 + j];
        *reinterpret_cast<f4*>(&out[(size_t)(c0 + r2) * out_ld + r0 + c2]) = pk.v;
    }
}

// bf16 -> bf16 transpose (K -> Ktg, V -> Vtg)
__global__ __launch_bounds__(256) void transpose_bf16(
    const u16* __restrict__ in, u16* __restrict__ out,
    int in_ld, int out_ld) {
    __shared__ u16 Ts[64][65];
    const int tid = threadIdx.x;
    const int r0 = blockIdx.y * 64, c0 = blockIdx.x * 64;
    #pragma unroll
    for (int l = 0; l < 2; ++l) {
        int f = tid + 256 * l, r = f >> 3, c = (f & 7) * 8;
        union { u16 u[8]; f4 v; } pk;
        pk.v = *reinterpret_cast<const f4*>(&in[(size_t)(r0 + r) * in_ld + c0 + c]);
        #pragma unroll
        for (int j = 0; j < 8; ++j) Ts[c + j][r] = pk.u[j];
    }
    __syncthreads();
    #pragma unroll
    for (int l = 0; l < 2; ++l) {
        int f = tid + 256 * l, r2 = f >> 3, c2 = (f & 7) * 8;
        union { u16 u[8]; f4 v; } pk;
        #pragma unroll
        for (int j = 0; j < 8; ++j) pk.u[j] = Ts[r2][c2 + j];
        *reinterpret_cast<f4*>(&out[(size_t)(c0 + r2) * out_ld + r0 + c2]) = pk.v;
    }
}

// ---------------- bf16 MFMA GEMM (unchanged from R4) ----------------
__device__ inline void gl_lds16(const void* g, void* l) {
    __builtin_amdgcn_global_load_lds(
        (const __attribute__((address_space(1))) void*)g,
        (__attribute__((address_space(3))) void*)l, 16, 0, 0);
}

template<bool OUT_BF16>
__global__ __launch_bounds__(256) void gemm_mfma(
    const u16* __restrict__ A, const u16* __restrict__ Bt,
    const float* __restrict__ bias, void* __restrict__ Cout,
    int M, int N, int K) {
    __shared__ u16 As[128][32];
    __shared__ u16 Bs[128][32];
    const int tid = threadIdx.x;
    const int m0 = blockIdx.y * 128, n0 = blockIdx.x * 128;
    const int w = tid >> 6, lid = tid & 63, ln = tid & 15, quad = (tid & 63) >> 4;
    const int wm = (w >> 1) * 64, wn = (w & 1) * 64;
    const int srow = lid >> 2, scol = (lid & 3) * 8;

    f32x4 acc[4][4];
    #pragma unroll
    for (int i = 0; i < 4; ++i)
        #pragma unroll
        for (int j = 0; j < 4; ++j) acc[i][j] = 0.f;

    for (int k0 = 0; k0 < K; k0 += 32) {
        __syncthreads();
        #pragma unroll
        for (int i = 0; i < 2; ++i) {
            const int rb = w * 16 + i * 64;
            gl_lds16(&A[(size_t)(m0 + rb + srow) * K + k0 + scol], &As[rb][0]);
            gl_lds16(&Bt[(size_t)(n0 + rb + srow) * K + k0 + scol], &Bs[rb][0]);
        }
        __syncthreads();
        s16x8 a[4], b[4];
        #pragma unroll
        for (int mt = 0; mt < 4; ++mt)
            a[mt] = *reinterpret_cast<const s16x8*>(&As[wm + mt * 16 + ln][quad * 8]);
        #pragma unroll
        for (int nt = 0; nt < 4; ++nt)
            b[nt] = *reinterpret_cast<const s16x8*>(&Bs[wn + nt * 16 + ln][quad * 8]);
        #pragma unroll
        for (int mt = 0; mt < 4; ++mt)
            #pragma unroll
            for (int nt = 0; nt < 4; ++nt)
                acc[mt][nt] = __builtin_amdgcn_mfma_f32_16x16x32_bf16(
                    a[mt], b[nt], acc[mt][nt], 0, 0, 0);
    }

    float bv[4];
    #pragma unroll
    for (int nt = 0; nt < 4; ++nt) bv[nt] = bias[n0 + wn + nt * 16 + ln];
    #pragma unroll
    for (int mt = 0; mt < 4; ++mt)
        #pragma unroll
        for (int nt = 0; nt < 4; ++nt)
            #pragma unroll
            for (int r = 0; r < 4; ++r) {
                int row = m0 + wm + mt * 16 + quad * 4 + r;
                int col = n0 + wn + nt * 16 + ln;
                float v = acc[mt][nt][r] + bv[nt];
                if (OUT_BF16) ((u16*)Cout)[(size_t)row * N + col] = f2bf(v);
                else          ((float*)Cout)[(size_t)row * N + col] = v;
            }
}

// ---------------- chunk state: G_c = K_c^T @ V_c, stored as P-layout [d_v][d_k] fp32 ----
// One wave per (head, chunk). A = K^T (rows of Ktg), B = V (rows of Vtg as B[k=t][n=d_v]).
// D[m=d_k][n=d_v]; store addr d_v*64 + d_k -> 4 contiguous f32 per (lane,quad): float4 store.
__global__ __launch_bounds__(256) void gchunk_kernel(
    const u16* __restrict__ Ktg, const u16* __restrict__ Vtg,
    float* __restrict__ Gt) {
    const int tid = threadIdx.x;
    const int w = tid >> 6, ln = tid & 15, quad = (tid & 63) >> 4;
    const int gw = blockIdx.x * 4 + w;
    const int h = gw & 15, c = gw >> 4;

    s16x8 kf[4][2], vf[4][2];
    #pragma unroll
    for (int mt = 0; mt < 4; ++mt)
        #pragma unroll
        for (int kk = 0; kk < 2; ++kk)
            kf[mt][kk] = *reinterpret_cast<const s16x8*>(
                &Ktg[(size_t)(h * DH + mt * 16 + ln) * TSEQ + c * 64 + kk * 32 + quad * 8]);
    #pragma unroll
    for (int nt = 0; nt < 4; ++nt)
        #pragma unroll
        for (int kk = 0; kk < 2; ++kk)
            vf[nt][kk] = *reinterpret_cast<const s16x8*>(
                &Vtg[(size_t)(h * DH + nt * 16 + ln) * TSEQ + c * 64 + kk * 32 + quad * 8]);

    f32x4 acc[4][4];
    #pragma unroll
    for (int i = 0; i < 4; ++i)
        #pragma unroll
        for (int j = 0; j < 4; ++j) acc[i][j] = 0.f;
    #pragma unroll
    for (int mt = 0; mt < 4; ++mt)
        #pragma unroll
        for (int nt = 0; nt < 4; ++nt)
            #pragma unroll
            for (int kk = 0; kk < 2; ++kk)
                acc[mt][nt] = __builtin_amdgcn_mfma_f32_16x16x32_bf16(
                    kf[mt][kk], vf[nt][kk], acc[mt][nt], 0, 0, 0);

    float* base = &Gt[((size_t)(c * 16 + h) << 12)];
    #pragma unroll
    for (int mt = 0; mt < 4; ++mt)
        #pragma unroll
        for (int nt = 0; nt < 4; ++nt)
            *reinterpret_cast<f4*>(
                &base[(nt * 16 + ln) * 64 + mt * 16 + quad * 4]) =
                make_float4(acc[mt][nt][0], acc[mt][nt][1],
                            acc[mt][nt][2], acc[mt][nt][3]);
}

// ---------------- exclusive prefix over chunks (fp32), emit bf16 P ----------------
// thread owns one (h, entry); 64 sequential chunk steps; fully coalesced.
__global__ __launch_bounds__(256) void prefix_scan(
    const float* __restrict__ Gt, u16* __restrict__ P) {
    const int t = blockIdx.x * 256 + threadIdx.x;   // 65536 threads
    const int h = t >> 12, e = t & 4095;
    float sum = 0.f;
    for (int c = 0; c < NCH; ++c) {
        size_t a = ((size_t)(c * 16 + h) << 12) + e;
        P[a] = f2bf(sum);
        sum += Gt[a];
    }
}

// ---------------- intra-chunk causal + inter-chunk Q@P ----------------
// Block = (chunk qt, head h), 4 waves x 16 q-rows. No __syncthreads at all
// (S round-trip is wave-private). 24 MFMAs/wave. Uniform work (scan absorbed
// the causal triangle).
__global__ __launch_bounds__(256, 2) void intra_mfma(
    const u16* __restrict__ kqvb, const u16* __restrict__ Vtg,
    const u16* __restrict__ P, u16* __restrict__ attnb) {
    __shared__ u16 Ss[4][16][72];   // per-wave S[q 16][s 64], stride 72 (144B)
    const int tid = threadIdx.x;
    const int w = tid >> 6, ln = tid & 15, quad = (tid & 63) >> 4;
    const int qt = blockIdx.x, h = blockIdx.y;
    const int q0 = qt * 64;

    // Q frags: lane ln <-> q-row (w*16+ln); serve as B in phase A and A in Q@P
    s16x8 qf[2];
    #pragma unroll
    for (int kk = 0; kk < 2; ++kk)
        qf[kk] = *reinterpret_cast<const s16x8*>(
            &kqvb[(size_t)(q0 + w * 16 + ln) * LD3 + DE + h * DH + kk * 32 + quad * 8]);

    // K frags (A-operand, m = s covering the whole 64-row chunk)
    s16x8 kf[4][2];
    #pragma unroll
    for (int mt = 0; mt < 4; ++mt)
        #pragma unroll
        for (int kk = 0; kk < 2; ++kk)
            kf[mt][kk] = *reinterpret_cast<const s16x8*>(
                &kqvb[(size_t)(q0 + mt * 16 + ln) * LD3 + h * DH + kk * 32 + quad * 8]);

    // phase A: S^T = K Q^T, diag mask, pack -> wave-private LDS as S[q][s]
    #pragma unroll
    for (int mt = 0; mt < 4; ++mt) {
        f32x4 s;
        s = 0.f;
        s = __builtin_amdgcn_mfma_f32_16x16x32_bf16(kf[mt][0], qf[0], s, 0, 0, 0);
        s = __builtin_amdgcn_mfma_f32_16x16x32_bf16(kf[mt][1], qf[1], s, 0, 0, 0);
        #pragma unroll
        for (int r = 0; r < 4; ++r)
            if (mt * 16 + quad * 4 + r > w * 16 + ln) s[r] = 0.f;   // s_local > q_local
        __hip_bfloat162 p0 = __float22bfloat162_rn(make_float2(s[0], s[1]));
        __hip_bfloat162 p1 = __float22bfloat162_rn(make_float2(s[2], s[3]));
        uint2 pk = make_uint2(*reinterpret_cast<unsigned int*>(&p0),
                              *reinterpret_cast<unsigned int*>(&p1));
        *reinterpret_cast<uint2*>(&Ss[w][ln][mt * 16 + quad * 4]) = pk;
    }

    // S frags back (A-operand: m=q=ln, k=s)
    s16x8 sf[2];
    #pragma unroll
    for (int kk = 0; kk < 2; ++kk)
        sf[kk] = *reinterpret_cast<const s16x8*>(&Ss[w][ln][kk * 32 + quad * 8]);

    f32x4 accO[4];
    #pragma unroll
    for (int nt = 0; nt < 4; ++nt) accO[nt] = 0.f;

    // phase B: O = S @ V  (B = V^T rows from Vtg)
    #pragma unroll
    for (int nt = 0; nt < 4; ++nt)
        #pragma unroll
        for (int kk = 0; kk < 2; ++kk) {
            s16x8 vf = *reinterpret_cast<const s16x8*>(
                &Vtg[(size_t)(h * DH + nt * 16 + ln) * TSEQ + q0 + kk * 32 + quad * 8]);
            accO[nt] = __builtin_amdgcn_mfma_f32_16x16x32_bf16(sf[kk], vf, accO[nt], 0, 0, 0);
        }

    // inter-chunk: O += Q @ P  (B = P rows [d_v][d_k])
    const u16* Pc = P + (((size_t)(qt * 16 + h)) << 12);
    #pragma unroll
    for (int nt = 0; nt < 4; ++nt)
        #pragma unroll
        for (int kk = 0; kk < 2; ++kk) {
            s16x8 pf = *reinterpret_cast<const s16x8*>(
                &Pc[(nt * 16 + ln) * 64 + kk * 32 + quad * 8]);
            accO[nt] = __builtin_amdgcn_mfma_f32_16x16x32_bf16(qf[kk], pf, accO[nt], 0, 0, 0);
        }

    #pragma unroll
    for (int nt = 0; nt < 4; ++nt)
        #pragma unroll
        for (int r = 0; r < 4; ++r)
            attnb[(size_t)(q0 + w * 16 + quad * 4 + r) * DE + h * DH + nt * 16 + ln] =
                f2bf(accO[nt][r]);
}

extern "C" void kernel_launch(void* const* d_in, const int* in_sizes, int n_in,
                              void* d_out, int out_size, void* d_ws, size_t ws_size,
                              hipStream_t stream) {
    const float* x  = (const float*)d_in[0];
    const float* W1 = (const float*)d_in[1];
    const float* b1 = (const float*)d_in[2];
    const float* W2 = (const float*)d_in[3];
    const float* b2 = (const float*)d_in[4];
    float* out = (float*)d_out;

    u16* xb    = (u16*)d_ws;                       // [4096][1024]; reused as P later
    u16* W1t   = xb    + (size_t)TSEQ * DE;        // [3072][1024]
    u16* W2t   = W1t   + (size_t)LD3 * DE;         // [1024][1024]
    u16* kqvb  = W2t   + (size_t)DE * DE;          // [4096][3072]
    u16* Ktg   = kqvb  + (size_t)TSEQ * LD3;       // [1024][4096]  K^T
    u16* Vtg   = Ktg   + (size_t)DE * TSEQ;        // [1024][4096]  V^T
    float* Gt  = (float*)(Vtg + (size_t)DE * TSEQ);// [64ch][16h][4096] fp32 (16.8MB)
    u16* P     = xb;                               // aliases xb (dead after gemm1)
    u16* attnb = (u16*)Gt;                         // aliases Gt (dead after prefix)

    cast_f32_bf16<<<(TSEQ * DE / 4 + 255) / 256, 256, 0, stream>>>(x, xb, TSEQ * DE / 4);
    transpose_cast_f32<<<dim3(LD3 / 64, DE / 64), 256, 0, stream>>>(W1, W1t, LD3, DE);
    transpose_cast_f32<<<dim3(DE / 64, DE / 64), 256, 0, stream>>>(W2, W2t, DE, DE);

    gemm_mfma<true><<<dim3(LD3 / 128, TSEQ / 128), 256, 0, stream>>>(
        xb, W1t, b1, kqvb, TSEQ, LD3, DE);

    transpose_bf16<<<dim3(DE / 64, TSEQ / 64), 256, 0, stream>>>(kqvb, Ktg, LD3, TSEQ);
    transpose_bf16<<<dim3(DE / 64, TSEQ / 64), 256, 0, stream>>>(
        kqvb + 2 * DE, Vtg, LD3, TSEQ);

    gchunk_kernel<<<NCH * NH / 4, 256, 0, stream>>>(Ktg, Vtg, Gt);
    prefix_scan<<<NH * 4096 / 256, 256, 0, stream>>>(Gt, P);
    intra_mfma<<<dim3(NCH, NH), 256, 0, stream>>>(kqvb, Vtg, P, attnb);

    gemm_mfma<false><<<dim3(DE / 128, TSEQ / 128), 256, 0, stream>>>(
        attnb, W2t, b2, out, TSEQ, DE, DE);
}

// Round 6
// 176.525 us; speedup vs baseline: 9.0322x; 1.0721x over previous
//
#include <hip/hip_runtime.h>
#include <hip/hip_bf16.h>

#define TSEQ 4096
#define DE   1024
#define NH   16
#define DH   64
#define LD3  3072
#define NCH  64          // chunks of 64 rows for the linear-attention scan

typedef float4 f4;
typedef unsigned short u16;
typedef __attribute__((ext_vector_type(8))) short s16x8;   // 8 bf16 MFMA A/B frag
typedef __attribute__((ext_vector_type(4))) float f32x4;   // MFMA C/D frag

__device__ inline u16 f2bf(float f) {
    unsigned int u = __float_as_uint(f);
    u += 0x7FFF + ((u >> 16) & 1);
    return (u16)(u >> 16);
}

__device__ inline void gl_lds16(const void* g, void* l) {
    __builtin_amdgcn_global_load_lds(
        (const __attribute__((address_space(1))) void*)g,
        (__attribute__((address_space(3))) void*)l, 16, 0, 0);
}

// ---------------- fused prep: cast x -> xb; W1 -> W1t; W2 -> W2t ----------------
// grid: [0,4096) cast x (1M float4); [4096,4864) W1 64x64 transpose tiles (16r x 48c);
//       [4864,5120) W2 tiles (16 x 16).
__global__ __launch_bounds__(256) void prep_kernel(
    const float* __restrict__ x, const float* __restrict__ W1,
    const float* __restrict__ W2, u16* __restrict__ xb,
    u16* __restrict__ W1t, u16* __restrict__ W2t) {
    __shared__ u16 Ts[64][65];
    const int b = blockIdx.x, tid = threadIdx.x;

    if (b < 4096) {   // cast x
        int i = b * 256 + tid;
        f4 v = *reinterpret_cast<const f4*>(&x[(size_t)i * 4]);
        ushort4 o = make_ushort4(f2bf(v.x), f2bf(v.y), f2bf(v.z), f2bf(v.w));
        *reinterpret_cast<ushort4*>(&xb[(size_t)i * 4]) = o;
        return;
    }
    const float* in; u16* out; int in_ld, out_ld, r0, c0;
    if (b < 4864) {
        int i = b - 4096;
        in = W1; out = W1t; in_ld = LD3; out_ld = DE;
        r0 = (i / 48) * 64; c0 = (i % 48) * 64;
    } else {
        int i = b - 4864;
        in = W2; out = W2t; in_ld = DE; out_ld = DE;
        r0 = (i / 16) * 64; c0 = (i % 16) * 64;
    }
    #pragma unroll
    for (int l = 0; l < 4; ++l) {
        int f = tid + 256 * l, r = f >> 4, c = (f & 15) * 4;
        f4 v = *reinterpret_cast<const f4*>(&in[(size_t)(r0 + r) * in_ld + c0 + c]);
        Ts[c + 0][r] = f2bf(v.x); Ts[c + 1][r] = f2bf(v.y);
        Ts[c + 2][r] = f2bf(v.z); Ts[c + 3][r] = f2bf(v.w);
    }
    __syncthreads();
    #pragma unroll
    for (int l = 0; l < 2; ++l) {
        int f = tid + 256 * l, r2 = f >> 3, c2 = (f & 7) * 8;
        union { u16 u[8]; f4 v; } pk;
        #pragma unroll
        for (int j = 0; j < 8; ++j) pk.u[j] = Ts[r2][c2 + j];
        *reinterpret_cast<f4*>(&out[(size_t)(c0 + r2) * out_ld + r0 + c2]) = pk.v;
    }
}

// ---------------- bf16 MFMA GEMM (m97-style, unchanged) ----------------
template<bool OUT_BF16>
__global__ __launch_bounds__(256) void gemm_mfma(
    const u16* __restrict__ A, const u16* __restrict__ Bt,
    const float* __restrict__ bias, void* __restrict__ Cout,
    int M, int N, int K) {
    __shared__ u16 As[128][32];
    __shared__ u16 Bs[128][32];
    const int tid = threadIdx.x;
    const int m0 = blockIdx.y * 128, n0 = blockIdx.x * 128;
    const int w = tid >> 6, lid = tid & 63, ln = tid & 15, quad = (tid & 63) >> 4;
    const int wm = (w >> 1) * 64, wn = (w & 1) * 64;
    const int srow = lid >> 2, scol = (lid & 3) * 8;

    f32x4 acc[4][4];
    #pragma unroll
    for (int i = 0; i < 4; ++i)
        #pragma unroll
        for (int j = 0; j < 4; ++j) acc[i][j] = 0.f;

    for (int k0 = 0; k0 < K; k0 += 32) {
        __syncthreads();
        #pragma unroll
        for (int i = 0; i < 2; ++i) {
            const int rb = w * 16 + i * 64;
            gl_lds16(&A[(size_t)(m0 + rb + srow) * K + k0 + scol], &As[rb][0]);
            gl_lds16(&Bt[(size_t)(n0 + rb + srow) * K + k0 + scol], &Bs[rb][0]);
        }
        __syncthreads();
        s16x8 a[4], b[4];
        #pragma unroll
        for (int mt = 0; mt < 4; ++mt)
            a[mt] = *reinterpret_cast<const s16x8*>(&As[wm + mt * 16 + ln][quad * 8]);
        #pragma unroll
        for (int nt = 0; nt < 4; ++nt)
            b[nt] = *reinterpret_cast<const s16x8*>(&Bs[wn + nt * 16 + ln][quad * 8]);
        #pragma unroll
        for (int mt = 0; mt < 4; ++mt)
            #pragma unroll
            for (int nt = 0; nt < 4; ++nt)
                acc[mt][nt] = __builtin_amdgcn_mfma_f32_16x16x32_bf16(
                    a[mt], b[nt], acc[mt][nt], 0, 0, 0);
    }

    float bv[4];
    #pragma unroll
    for (int nt = 0; nt < 4; ++nt) bv[nt] = bias[n0 + wn + nt * 16 + ln];
    #pragma unroll
    for (int mt = 0; mt < 4; ++mt)
        #pragma unroll
        for (int nt = 0; nt < 4; ++nt)
            #pragma unroll
            for (int r = 0; r < 4; ++r) {
                int row = m0 + wm + mt * 16 + quad * 4 + r;
                int col = n0 + wn + nt * 16 + ln;
                float v = acc[mt][nt][r] + bv[nt];
                if (OUT_BF16) ((u16*)Cout)[(size_t)row * N + col] = f2bf(v);
                else          ((float*)Cout)[(size_t)row * N + col] = v;
            }
}

// ---------------- chunk state: G_c = K_c^T @ V_c -> Gt [(c*16+h)][d_v*64+d_k] fp32 ----
// Block = one (chunk c, head h). Cooperative LDS transpose of the 64x64 K,V slices,
// then wave w computes the d_k rows [w*16, w*16+16) of G.
__global__ __launch_bounds__(256, 2) void gchunk_kernel(
    const u16* __restrict__ kqvb, float* __restrict__ Gt) {
    __shared__ u16 KT[64][72];   // KT[d_k][t]
    __shared__ u16 VT[64][72];   // VT[d_v][t]
    const int tid = threadIdx.x;
    const int w = tid >> 6, ln = tid & 15, quad = (tid & 63) >> 4;
    const int c = blockIdx.x, h = blockIdx.y;

    #pragma unroll
    for (int l = 0; l < 2; ++l) {
        int idx = tid + 256 * l, t = idx >> 3, dc = (idx & 7) * 8;
        const size_t rb = (size_t)(c * 64 + t) * LD3 + h * DH + dc;
        union { u16 u[8]; f4 v; } pk;
        pk.v = *reinterpret_cast<const f4*>(&kqvb[rb]);            // K
        #pragma unroll
        for (int j = 0; j < 8; ++j) KT[dc + j][t] = pk.u[j];
        pk.v = *reinterpret_cast<const f4*>(&kqvb[rb + 2 * DE]);   // V
        #pragma unroll
        for (int j = 0; j < 8; ++j) VT[dc + j][t] = pk.u[j];
    }
    __syncthreads();

    s16x8 kf[2];
    #pragma unroll
    for (int kk = 0; kk < 2; ++kk)
        kf[kk] = *reinterpret_cast<const s16x8*>(&KT[w * 16 + ln][kk * 32 + quad * 8]);

    f32x4 acc[4];
    #pragma unroll
    for (int nt = 0; nt < 4; ++nt) acc[nt] = 0.f;
    #pragma unroll
    for (int nt = 0; nt < 4; ++nt)
        #pragma unroll
        for (int kk = 0; kk < 2; ++kk) {
            s16x8 vf = *reinterpret_cast<const s16x8*>(&VT[nt * 16 + ln][kk * 32 + quad * 8]);
            acc[nt] = __builtin_amdgcn_mfma_f32_16x16x32_bf16(kf[kk], vf, acc[nt], 0, 0, 0);
        }

    float* base = &Gt[((size_t)(c * 16 + h) << 12)];
    #pragma unroll
    for (int nt = 0; nt < 4; ++nt)
        *reinterpret_cast<f4*>(&base[(nt * 16 + ln) * 64 + w * 16 + quad * 4]) =
            make_float4(acc[nt][0], acc[nt][1], acc[nt][2], acc[nt][3]);
}

// ---------------- exclusive prefix over chunks (fp32), emit bf16 P ----------------
__global__ __launch_bounds__(256) void prefix_scan(
    const float* __restrict__ Gt, u16* __restrict__ P) {
    const int t = blockIdx.x * 256 + threadIdx.x;   // 65536 threads
    const int h = t >> 12, e = t & 4095;
    const size_t stride = (size_t)16 << 12;
    size_t a = ((size_t)h << 12) + e;
    float sum = 0.f;
    float nxt = Gt[a];
    for (int c = 0; c < NCH; ++c) {
        float cur = nxt;
        if (c + 1 < NCH) nxt = Gt[a + stride];   // prefetch next chunk's term
        P[a] = f2bf(sum);
        sum += cur;
        a += stride;
    }
}

// ---------------- intra-chunk causal + inter-chunk Q@P ----------------
// Block = (chunk qt, head h); cooperative LDS transpose of V chunk (one barrier),
// then 4 waves x 16 q-rows, wave-private S round-trip, 26 MFMAs/wave.
__global__ __launch_bounds__(256, 2) void intra_mfma(
    const u16* __restrict__ kqvb, const u16* __restrict__ P,
    u16* __restrict__ attnb) {
    __shared__ u16 VT[64][72];      // VT[d_v][s_local]
    __shared__ u16 Ss[4][16][72];   // per-wave S[q 16][s 64]
    const int tid = threadIdx.x;
    const int w = tid >> 6, ln = tid & 15, quad = (tid & 63) >> 4;
    const int qt = blockIdx.x, h = blockIdx.y;
    const int q0 = qt * 64;

    // cooperative V transpose (independent of the Q/K frag loads below)
    #pragma unroll
    for (int l = 0; l < 2; ++l) {
        int idx = tid + 256 * l, t = idx >> 3, dc = (idx & 7) * 8;
        union { u16 u[8]; f4 v; } pk;
        pk.v = *reinterpret_cast<const f4*>(
            &kqvb[(size_t)(q0 + t) * LD3 + 2 * DE + h * DH + dc]);
        #pragma unroll
        for (int j = 0; j < 8; ++j) VT[dc + j][t] = pk.u[j];
    }

    // Q frags: lane ln <-> q-row (w*16+ln); B-operand in phase A, A-operand in Q@P
    s16x8 qf[2];
    #pragma unroll
    for (int kk = 0; kk < 2; ++kk)
        qf[kk] = *reinterpret_cast<const s16x8*>(
            &kqvb[(size_t)(q0 + w * 16 + ln) * LD3 + DE + h * DH + kk * 32 + quad * 8]);

    // K frags (A-operand, m = s covering the whole 64-row chunk)
    s16x8 kf[4][2];
    #pragma unroll
    for (int mt = 0; mt < 4; ++mt)
        #pragma unroll
        for (int kk = 0; kk < 2; ++kk)
            kf[mt][kk] = *reinterpret_cast<const s16x8*>(
                &kqvb[(size_t)(q0 + mt * 16 + ln) * LD3 + h * DH + kk * 32 + quad * 8]);

    __syncthreads();   // VT ready

    // phase A: S^T = K Q^T, diag mask, pack -> wave-private LDS as S[q][s]
    #pragma unroll
    for (int mt = 0; mt < 4; ++mt) {
        f32x4 s;
        s = 0.f;
        s = __builtin_amdgcn_mfma_f32_16x16x32_bf16(kf[mt][0], qf[0], s, 0, 0, 0);
        s = __builtin_amdgcn_mfma_f32_16x16x32_bf16(kf[mt][1], qf[1], s, 0, 0, 0);
        #pragma unroll
        for (int r = 0; r < 4; ++r)
            if (mt * 16 + quad * 4 + r > w * 16 + ln) s[r] = 0.f;   // s_local > q_local
        __hip_bfloat162 p0 = __float22bfloat162_rn(make_float2(s[0], s[1]));
        __hip_bfloat162 p1 = __float22bfloat162_rn(make_float2(s[2], s[3]));
        uint2 pk = make_uint2(*reinterpret_cast<unsigned int*>(&p0),
                              *reinterpret_cast<unsigned int*>(&p1));
        *reinterpret_cast<uint2*>(&Ss[w][ln][mt * 16 + quad * 4]) = pk;
    }

    s16x8 sf[2];
    #pragma unroll
    for (int kk = 0; kk < 2; ++kk)
        sf[kk] = *reinterpret_cast<const s16x8*>(&Ss[w][ln][kk * 32 + quad * 8]);

    f32x4 accO[4];
    #pragma unroll
    for (int nt = 0; nt < 4; ++nt) accO[nt] = 0.f;

    // phase B: O = S @ V  (B-frags = rows of VT)
    #pragma unroll
    for (int nt = 0; nt < 4; ++nt)
        #pragma unroll
        for (int kk = 0; kk < 2; ++kk) {
            s16x8 vf = *reinterpret_cast<const s16x8*>(&VT[nt * 16 + ln][kk * 32 + quad * 8]);
            accO[nt] = __builtin_amdgcn_mfma_f32_16x16x32_bf16(sf[kk], vf, accO[nt], 0, 0, 0);
        }

    // inter-chunk: O += Q @ P  (B-frags = rows of P [d_v][d_k])
    const u16* Pc = P + (((size_t)(qt * 16 + h)) << 12);
    #pragma unroll
    for (int nt = 0; nt < 4; ++nt)
        #pragma unroll
        for (int kk = 0; kk < 2; ++kk) {
            s16x8 pf = *reinterpret_cast<const s16x8*>(
                &Pc[(nt * 16 + ln) * 64 + kk * 32 + quad * 8]);
            accO[nt] = __builtin_amdgcn_mfma_f32_16x16x32_bf16(qf[kk], pf, accO[nt], 0, 0, 0);
        }

    #pragma unroll
    for (int nt = 0; nt < 4; ++nt)
        #pragma unroll
        for (int r = 0; r < 4; ++r)
            attnb[(size_t)(q0 + w * 16 + quad * 4 + r) * DE + h * DH + nt * 16 + ln] =
                f2bf(accO[nt][r]);
}

extern "C" void kernel_launch(void* const* d_in, const int* in_sizes, int n_in,
                              void* d_out, int out_size, void* d_ws, size_t ws_size,
                              hipStream_t stream) {
    const float* x  = (const float*)d_in[0];
    const float* W1 = (const float*)d_in[1];
    const float* b1 = (const float*)d_in[2];
    const float* W2 = (const float*)d_in[3];
    const float* b2 = (const float*)d_in[4];
    float* out = (float*)d_out;

    u16* xb    = (u16*)d_ws;                       // [4096][1024]; reused as P later
    u16* W1t   = xb    + (size_t)TSEQ * DE;        // [3072][1024]
    u16* W2t   = W1t   + (size_t)LD3 * DE;         // [1024][1024]
    u16* kqvb  = W2t   + (size_t)DE * DE;          // [4096][3072]
    float* Gt  = (float*)(kqvb + (size_t)TSEQ * LD3); // [64ch*16h][4096] fp32 (16.8MB)
    u16* P     = xb;                               // aliases xb (dead after gemm1)
    u16* attnb = (u16*)Gt;                         // aliases Gt (dead after prefix)

    prep_kernel<<<5120, 256, 0, stream>>>(x, W1, W2, xb, W1t, W2t);

    gemm_mfma<true><<<dim3(LD3 / 128, TSEQ / 128), 256, 0, stream>>>(
        xb, W1t, b1, kqvb, TSEQ, LD3, DE);

    gchunk_kernel<<<dim3(NCH, NH), 256, 0, stream>>>(kqvb, Gt);
    prefix_scan<<<NH * 4096 / 256, 256, 0, stream>>>(Gt, P);
    intra_mfma<<<dim3(NCH, NH), 256, 0, stream>>>(kqvb, P, attnb);

    gemm_mfma<false><<<dim3(DE / 128, TSEQ / 128), 256, 0, stream>>>(
        attnb, W2t, b2, out, TSEQ, DE, DE);
}